// Round 2
// baseline (713.625 us; speedup 1.0000x reference)
//
#include <hip/hip_runtime.h>

#define N_NODES 100000
#define N_EDGES 3200000
#define IN_FEATS 256
#define N_HEADS 8
#define OUT_FEATS 32
#define NEG_SLOPE 0.2f
#define K_STASH 40

// ---------------- kernel 1: fold W with attn_l/attn_r -> wlr[256][16] ----------------
__global__ void k_wlr(const float* __restrict__ W, const float* __restrict__ al,
                      const float* __restrict__ ar, float* __restrict__ wlr) {
    int t = blockIdx.x * blockDim.x + threadIdx.x;
    if (t >= 256 * 16) return;
    int k = t >> 4, j = t & 15;
    int h = j & 7;
    const float* av = (j < 8) ? al : ar;
    const float* wrow = W + k * 256 + h * 32;
    float s = 0.f;
#pragma unroll
    for (int f = 0; f < 32; ++f) s += wrow[f] * av[h * 32 + f];
    wlr[k * 16 + j] = s;
}

// ---------------- kernel 2: elr = feat @ wlr (one wave per row) ----------------
__global__ void __launch_bounds__(256) k_elr(const float* __restrict__ feat,
                                             const float* __restrict__ wlr,
                                             float* __restrict__ elr) {
    int lane = threadIdx.x & 63;
    int gwave = (blockIdx.x * blockDim.x + threadIdx.x) >> 6;
    int nwaves = (gridDim.x * blockDim.x) >> 6;

    float w[4][16];
#pragma unroll
    for (int i = 0; i < 4; ++i)
#pragma unroll
        for (int j4 = 0; j4 < 4; ++j4) {
            float4 v = *(const float4*)(wlr + (lane * 4 + i) * 16 + j4 * 4);
            w[i][j4 * 4 + 0] = v.x; w[i][j4 * 4 + 1] = v.y;
            w[i][j4 * 4 + 2] = v.z; w[i][j4 * 4 + 3] = v.w;
        }

    for (int row = gwave; row < N_NODES; row += nwaves) {
        float4 f4 = *(const float4*)(feat + row * 256 + lane * 4);
        float acc[16];
#pragma unroll
        for (int j = 0; j < 16; ++j)
            acc[j] = f4.x * w[0][j] + f4.y * w[1][j] + f4.z * w[2][j] + f4.w * w[3][j];
#pragma unroll
        for (int m = 1; m < 64; m <<= 1)
#pragma unroll
            for (int j = 0; j < 16; ++j)
                acc[j] += __shfl_xor(acc[j], m, 64);
        if (lane == 0) {
            float4* o = (float4*)(elr + row * 16);
            o[0] = make_float4(acc[0], acc[1], acc[2], acc[3]);
            o[1] = make_float4(acc[4], acc[5], acc[6], acc[7]);
            o[2] = make_float4(acc[8], acc[9], acc[10], acc[11]);
            o[3] = make_float4(acc[12], acc[13], acc[14], acc[15]);
        }
    }
}

// ---------------- CSR build ----------------
__global__ void k_count(const int* __restrict__ dst, int* __restrict__ cnt) {
    int e = blockIdx.x * 256 + threadIdx.x;
    if (e < N_EDGES) atomicAdd(&cnt[dst[e]], 1);
}

__global__ void k_scan1(const int* __restrict__ cnt, int* __restrict__ ofs,
                        int* __restrict__ bsum) {
    __shared__ int s[256];
    int t = blockIdx.x * 256 + threadIdx.x;
    int x = (t < N_NODES) ? cnt[t] : 0;
    s[threadIdx.x] = x;
    __syncthreads();
    int v = x;
    for (int d = 1; d < 256; d <<= 1) {
        int y = (threadIdx.x >= d) ? s[threadIdx.x - d] : 0;
        __syncthreads();
        v += y;
        s[threadIdx.x] = v;
        __syncthreads();
    }
    if (t < N_NODES) ofs[t] = v - x;              // exclusive within block
    if (threadIdx.x == 255) bsum[blockIdx.x] = v; // block total
}

__global__ void k_scan2(int* __restrict__ bsum, int nb) {
    __shared__ int s[512];
    int t = threadIdx.x;
    int x = (t < nb) ? bsum[t] : 0;
    s[t] = x;
    __syncthreads();
    int v = x;
    for (int d = 1; d < 512; d <<= 1) {
        int y = (t >= d) ? s[t - d] : 0;
        __syncthreads();
        v += y;
        s[t] = v;
        __syncthreads();
    }
    if (t < nb) bsum[t] = v - x;                  // exclusive block offsets
}

__global__ void k_scan3(int* __restrict__ ofs, const int* __restrict__ bsum,
                        int* __restrict__ cursor) {
    int t = blockIdx.x * 256 + threadIdx.x;
    if (t < N_NODES) {
        int v = ofs[t] + bsum[blockIdx.x];
        ofs[t] = v;
        cursor[t] = v;
    }
    if (t == 0) ofs[N_NODES] = N_EDGES;
}

__global__ void k_scatter(const int* __restrict__ dst, int* __restrict__ cursor,
                          int* __restrict__ eidx) {
    int e = blockIdx.x * 256 + threadIdx.x;
    if (e < N_EDGES) {
        int p = atomicAdd(&cursor[dst[e]], 1);
        eidx[p] = e;
    }
}

// ---------------- main pull kernel: 8 lanes per dst node (lane = head) ----------------
__global__ void __launch_bounds__(256) k_nodesum(
    const int* __restrict__ ofs, const int* __restrict__ eidx,
    const int* __restrict__ src, const float* __restrict__ elr,
    float* __restrict__ out)
{
    int t = blockIdx.x * 256 + threadIdx.x;
    int g = t >> 3;                    // node id (3125*256/8 == 100000 exact)
    int h = t & 7;                     // head
    int beg = ofs[g], end = ofs[g + 1];
    int deg = end - beg;
    if (deg == 0) return;
    float er = elr[g * 16 + 8 + h];
    float sum = 0.f;
    float ez[K_STASH];                 // statically indexed only (unrolled)
#pragma unroll
    for (int ci = 0; ci < K_STASH; ++ci) {
        if (ci < deg) {
            int eid = eidx[beg + ci];
            float el = elr[src[eid] * 16 + h];
            float v = el + er;
            v = v > 0.f ? v : NEG_SLOPE * v;
            float z = __expf(v);
            ez[ci] = z;
            sum += z;
        }
    }
    for (int i = K_STASH; i < deg; ++i) {      // rare tail (deg > 40)
        int eid = eidx[beg + i];
        float el = elr[src[eid] * 16 + h];
        float v = el + er;
        v = v > 0.f ? v : NEG_SLOPE * v;
        sum += __expf(v);
    }
    float rs = 1.0f / sum;
#pragma unroll
    for (int ci = 0; ci < K_STASH; ++ci) {
        if (ci < deg) {
            int eid = eidx[beg + ci];          // re-read: broadcast, L1-hot
            out[eid * 8 + h] = ez[ci] * rs;
        }
    }
    for (int i = K_STASH; i < deg; ++i) {
        int eid = eidx[beg + i];
        float el = elr[src[eid] * 16 + h];
        float v = el + er;
        v = v > 0.f ? v : NEG_SLOPE * v;
        out[eid * 8 + h] = __expf(v) * rs;
    }
}

// ---------------- fallback path (round-1 algorithm) if ws too small ----------------
__global__ void k_expsum(const int* __restrict__ src, const int* __restrict__ dst,
                         const float* __restrict__ elr, float* __restrict__ ssum) {
    int t = blockIdx.x * 256 + threadIdx.x;
    int e = t >> 3, h = t & 7;
    int sn = src[e], dn = dst[e];
    float v = elr[sn * 16 + h] + elr[dn * 16 + 8 + h];
    v = v > 0.f ? v : NEG_SLOPE * v;
    atomicAdd(ssum + dn * 8 + h, __expf(v));
}

__global__ void k_norm(const int* __restrict__ src, const int* __restrict__ dst,
                       const float* __restrict__ elr, const float* __restrict__ ssum,
                       float* __restrict__ out) {
    int t = blockIdx.x * 256 + threadIdx.x;
    int e = t >> 3, h = t & 7;
    int sn = src[e], dn = dst[e];
    float v = elr[sn * 16 + h] + elr[dn * 16 + 8 + h];
    v = v > 0.f ? v : NEG_SLOPE * v;
    out[t] = __expf(v) / ssum[dn * 8 + h];
}

extern "C" void kernel_launch(void* const* d_in, const int* in_sizes, int n_in,
                              void* d_out, int out_size, void* d_ws, size_t ws_size,
                              hipStream_t stream) {
    const float* feat = (const float*)d_in[0];
    const float* W    = (const float*)d_in[1];
    const float* al   = (const float*)d_in[2];
    const float* ar   = (const float*)d_in[3];
    const int*   src  = (const int*)d_in[4];
    const int*   dst  = (const int*)d_in[5];
    float* out = (float*)d_out;

    char* ws = (char*)d_ws;
    // layout (16B-aligned chunks)
    size_t o_wlr    = 0;                        // 16 KB
    size_t o_elr    = o_wlr + 16384;            // 6.4 MB
    size_t o_ofs    = o_elr + (size_t)N_NODES * 16 * 4;       // 400016 B
    size_t o_cursor = o_ofs + ((size_t)(N_NODES + 1) * 4 + 15 & ~(size_t)15);
    size_t o_bsum   = o_cursor + (size_t)N_NODES * 4;         // 2 KB
    size_t o_cnt    = o_bsum + 2048;
    size_t o_eidx   = o_cnt + (size_t)N_NODES * 4;
    size_t need     = o_eidx + (size_t)N_EDGES * 4;

    float* wlr = (float*)(ws + o_wlr);
    float* elr = (float*)(ws + o_elr);

    k_wlr<<<16, 256, 0, stream>>>(W, al, ar, wlr);
    k_elr<<<2048, 256, 0, stream>>>(feat, wlr, elr);

    if (ws_size >= need) {
        int* ofs    = (int*)(ws + o_ofs);
        int* cursor = (int*)(ws + o_cursor);
        int* bsum   = (int*)(ws + o_bsum);
        int* cnt    = (int*)(ws + o_cnt);
        int* eidx   = (int*)(ws + o_eidx);
        const int NBLK_N = (N_NODES + 255) / 256;   // 391

        hipMemsetAsync(cnt, 0, (size_t)N_NODES * 4, stream);
        k_count<<<N_EDGES / 256, 256, 0, stream>>>(dst, cnt);
        k_scan1<<<NBLK_N, 256, 0, stream>>>(cnt, ofs, bsum);
        k_scan2<<<1, 512, 0, stream>>>(bsum, NBLK_N);
        k_scan3<<<NBLK_N, 256, 0, stream>>>(ofs, bsum, cursor);
        k_scatter<<<N_EDGES / 256, 256, 0, stream>>>(dst, cursor, eidx);
        k_nodesum<<<(N_NODES * 8) / 256, 256, 0, stream>>>(ofs, eidx, src, elr, out);
    } else {
        // fallback: atomic two-pass (round-1 path)
        float* ssum = (float*)(ws + o_ofs);
        hipMemsetAsync(ssum, 0, (size_t)N_NODES * 8 * 4, stream);
        int nblk = (N_EDGES * 8) / 256;
        k_expsum<<<nblk, 256, 0, stream>>>(src, dst, elr, ssum);
        k_norm<<<nblk, 256, 0, stream>>>(src, dst, elr, ssum, out);
    }
}

// Round 3
// 466.770 us; speedup vs baseline: 1.5289x; 1.5289x over previous
//
#include <hip/hip_runtime.h>

#define N_NODES 100000
#define N_EDGES 3200000
#define N_HEADS 8
#define NEG_SLOPE 0.2f

#define SH 9
#define RNG 512                   // nodes per bucket (1<<SH)
#define NBKT 196                  // ceil(100000/512)
#define BPB 4                     // blocks (and sum replicas) per bucket
#define NB_S 782                  // ceil(E / 4096) scatter/hist blocks

// ---------------- kernel 1: fold W with attn_l/attn_r -> wlr[256][16] ----------------
__global__ void k_wlr(const float* __restrict__ W, const float* __restrict__ al,
                      const float* __restrict__ ar, float* __restrict__ wlr) {
    int t = blockIdx.x * blockDim.x + threadIdx.x;
    if (t >= 256 * 16) return;
    int k = t >> 4, j = t & 15;
    int h = j & 7;
    const float* av = (j < 8) ? al : ar;
    const float* wrow = W + k * 256 + h * 32;
    float s = 0.f;
#pragma unroll
    for (int f = 0; f < 32; ++f) s += wrow[f] * av[h * 32 + f];
    wlr[k * 16 + j] = s;
}

// ---------------- kernel 2: elr = feat @ wlr (one wave per row) ----------------
__global__ void __launch_bounds__(256) k_elr(const float* __restrict__ feat,
                                             const float* __restrict__ wlr,
                                             float* __restrict__ elr) {
    int lane = threadIdx.x & 63;
    int gwave = (blockIdx.x * blockDim.x + threadIdx.x) >> 6;
    int nwaves = (gridDim.x * blockDim.x) >> 6;

    float w[4][16];
#pragma unroll
    for (int i = 0; i < 4; ++i)
#pragma unroll
        for (int j4 = 0; j4 < 4; ++j4) {
            float4 v = *(const float4*)(wlr + (lane * 4 + i) * 16 + j4 * 4);
            w[i][j4 * 4 + 0] = v.x; w[i][j4 * 4 + 1] = v.y;
            w[i][j4 * 4 + 2] = v.z; w[i][j4 * 4 + 3] = v.w;
        }

    for (int row = gwave; row < N_NODES; row += nwaves) {
        float4 f4 = *(const float4*)(feat + row * 256 + lane * 4);
        float acc[16];
#pragma unroll
        for (int j = 0; j < 16; ++j)
            acc[j] = f4.x * w[0][j] + f4.y * w[1][j] + f4.z * w[2][j] + f4.w * w[3][j];
#pragma unroll
        for (int m = 1; m < 64; m <<= 1)
#pragma unroll
            for (int j = 0; j < 16; ++j)
                acc[j] += __shfl_xor(acc[j], m, 64);
        if (lane == 0) {
            float4* o = (float4*)(elr + row * 16);
            o[0] = make_float4(acc[0], acc[1], acc[2], acc[3]);
            o[1] = make_float4(acc[4], acc[5], acc[6], acc[7]);
            o[2] = make_float4(acc[8], acc[9], acc[10], acc[11]);
            o[3] = make_float4(acc[12], acc[13], acc[14], acc[15]);
        }
    }
}

// ---------------- bucket histogram (coarse: dst>>SH) ----------------
__global__ void __launch_bounds__(256) k_hist(const int* __restrict__ dst,
                                              int* __restrict__ bktcnt) {
    __shared__ int h[NBKT];
    for (int i = threadIdx.x; i < NBKT; i += 256) h[i] = 0;
    __syncthreads();
    int base = blockIdx.x * 4096;
#pragma unroll
    for (int i = 0; i < 16; ++i) {
        int e = base + i * 256 + threadIdx.x;
        if (e < N_EDGES) atomicAdd(&h[dst[e] >> SH], 1);
    }
    __syncthreads();
    for (int i = threadIdx.x; i < NBKT; i += 256)
        if (h[i]) atomicAdd(&bktcnt[i], h[i]);
}

// ---------------- bucket offsets scan (1 block) ----------------
__global__ void k_bscan(const int* __restrict__ bktcnt, int* __restrict__ bktofs,
                        int* __restrict__ bktcur) {
    __shared__ int s[256];
    int t = threadIdx.x;
    int x = (t < NBKT) ? bktcnt[t] : 0;
    s[t] = x;
    __syncthreads();
    int v = x;
    for (int d = 1; d < 256; d <<= 1) {
        int y = (t >= d) ? s[t - d] : 0;
        __syncthreads();
        v += y;
        s[t] = v;
        __syncthreads();
    }
    if (t < NBKT) { bktofs[t] = v - x; bktcur[t] = v - x; }
    if (t == 0) bktofs[NBKT] = N_EDGES;
}

// ---------------- block-aggregated bucket scatter: packed = (dloc<<17)|src ----------------
__global__ void __launch_bounds__(256) k_scat(const int* __restrict__ src,
                                              const int* __restrict__ dst,
                                              int* __restrict__ bktcur,
                                              unsigned* __restrict__ packed) {
    __shared__ int lh[NBKT];
    __shared__ int lbase[NBKT];
    for (int i = threadIdx.x; i < NBKT; i += 256) lh[i] = 0;
    __syncthreads();
    int base = blockIdx.x * 4096;
    int dv[16];
#pragma unroll
    for (int i = 0; i < 16; ++i) {
        int e = base + i * 256 + threadIdx.x;
        dv[i] = (e < N_EDGES) ? dst[e] : -1;
        if (dv[i] >= 0) atomicAdd(&lh[dv[i] >> SH], 1);
    }
    __syncthreads();
    for (int i = threadIdx.x; i < NBKT; i += 256) {
        int c = lh[i];
        lbase[i] = c ? atomicAdd(&bktcur[i], c) : 0;
        lh[i] = 0;
    }
    __syncthreads();
#pragma unroll
    for (int i = 0; i < 16; ++i) {
        int e = base + i * 256 + threadIdx.x;
        if (dv[i] >= 0) {
            int b = dv[i] >> SH;
            int r = atomicAdd(&lh[b], 1);
            unsigned p = ((unsigned)(dv[i] & (RNG - 1)) << 17) | (unsigned)src[e];
            packed[lbase[b] + r] = p;
        }
    }
}

// ---------------- bucketed exp-sum: LDS-private accumulators, replica flush ----------------
__global__ void __launch_bounds__(256) k_bsum(const unsigned* __restrict__ packed,
                                              const int* __restrict__ bktofs,
                                              const float* __restrict__ elr,
                                              float* __restrict__ repl) {
    __shared__ float zss[RNG * 8];
    __shared__ float ers[RNG * 8];
    int b = blockIdx.x / BPB, q = blockIdx.x % BPB;
    int nbase = b << SH;
    int nlim = min(RNG, N_NODES - nbase);
    for (int i = threadIdx.x; i < RNG * 8; i += 256) zss[i] = 0.f;
    for (int i = threadIdx.x; i < nlim * 8; i += 256) {
        int n = i >> 3, h = i & 7;
        ers[i] = elr[(nbase + n) * 16 + 8 + h];
    }
    __syncthreads();
    int beg = bktofs[b], end = bktofs[b + 1];
    int len = end - beg;
    int chunk = (len + BPB - 1) / BPB;
    int s0 = beg + q * chunk, s1 = min(s0 + chunk, end);
    int h = threadIdx.x & 7;
    for (int i = s0 + (threadIdx.x >> 3); i < s1; i += 32) {
        unsigned p = packed[i];
        int srcn = p & 0x1FFFF;
        int dloc = p >> 17;
        float v = elr[srcn * 16 + h] + ers[dloc * 8 + h];
        v = v > 0.f ? v : NEG_SLOPE * v;
        atomicAdd(&zss[dloc * 8 + h], __expf(v));
    }
    __syncthreads();
    float* r = repl + (size_t)q * (N_NODES * 8);
    for (int i = threadIdx.x; i < nlim * 8; i += 256) r[nbase * 8 + i] = zss[i];
}

// ---------------- fold replicas -> dstpack[n][16] = {er[0..7], 1/s[0..7]} ----------------
__global__ void k_reduce(const float* __restrict__ repl, const float* __restrict__ elr,
                         float* __restrict__ dstpack) {
    int i = blockIdx.x * 256 + threadIdx.x;     // i < N*8 (exact grid)
    float s = 0.f;
#pragma unroll
    for (int q = 0; q < BPB; ++q) s += repl[(size_t)q * (N_NODES * 8) + i];
    int n = i >> 3, h = i & 7;
    dstpack[n * 16 + h] = elr[n * 16 + 8 + h];
    dstpack[n * 16 + 8 + h] = 1.0f / s;
}

// ---------------- streaming normalize: coalesced output ----------------
__global__ void __launch_bounds__(256) k_norm2(const int* __restrict__ src,
                                               const int* __restrict__ dst,
                                               const float* __restrict__ elr,
                                               const float* __restrict__ dstpack,
                                               float* __restrict__ out) {
    int t = blockIdx.x * 256 + threadIdx.x;
    int e = t >> 3, h = t & 7;
    int sn = src[e], dn = dst[e];
    float el = elr[sn * 16 + h];
    float er = dstpack[dn * 16 + h];
    float rs = dstpack[dn * 16 + 8 + h];
    float v = el + er;
    v = v > 0.f ? v : NEG_SLOPE * v;
    out[t] = __expf(v) * rs;
}

extern "C" void kernel_launch(void* const* d_in, const int* in_sizes, int n_in,
                              void* d_out, int out_size, void* d_ws, size_t ws_size,
                              hipStream_t stream) {
    const float* feat = (const float*)d_in[0];
    const float* W    = (const float*)d_in[1];
    const float* al   = (const float*)d_in[2];
    const float* ar   = (const float*)d_in[3];
    const int*   src  = (const int*)d_in[4];
    const int*   dst  = (const int*)d_in[5];
    float* out = (float*)d_out;

    // ws layout (~12.9 MB)
    char* ws = (char*)d_ws;
    float* wlr     = (float*)ws;                                   // 16 KB
    float* elr     = (float*)(ws + 16384);                         // 6.4 MB
    float* dstpack = (float*)(ws + 16384 + (size_t)N_NODES * 16 * 4);   // 6.4 MB
    char*  ip      = ws + 16384 + 2 * (size_t)N_NODES * 16 * 4;
    int* bktcnt = (int*)ip;                                        // NBKT
    int* bktofs = (int*)(ip + 1024);                               // NBKT+1
    int* bktcur = (int*)(ip + 2048);                               // NBKT

    // d_out doubles as scratch before the final full overwrite:
    unsigned* packed = (unsigned*)d_out;                 // [E) u32
    float*    repl   = (float*)d_out + N_EDGES;          // [BPB][N*8] f32

    hipMemsetAsync(bktcnt, 0, NBKT * 4, stream);

    k_wlr<<<16, 256, 0, stream>>>(W, al, ar, wlr);
    k_hist<<<NB_S, 256, 0, stream>>>(dst, bktcnt);
    k_bscan<<<1, 256, 0, stream>>>(bktcnt, bktofs, bktcur);
    k_scat<<<NB_S, 256, 0, stream>>>(src, dst, bktcur, packed);
    k_elr<<<2048, 256, 0, stream>>>(feat, wlr, elr);
    k_bsum<<<NBKT * BPB, 256, 0, stream>>>(packed, bktofs, elr, repl);
    k_reduce<<<(N_NODES * 8) / 256, 256, 0, stream>>>(repl, elr, dstpack);
    k_norm2<<<(N_EDGES * 8) / 256, 256, 0, stream>>>(src, dst, elr, dstpack, out);
}

// Round 4
// 421.385 us; speedup vs baseline: 1.6935x; 1.1077x over previous
//
#include <hip/hip_runtime.h>

#define N_NODES 100000
#define N_EDGES 3200000
#define NEG_SLOPE 0.2f

#define SH 9
#define RNG 512                   // nodes per bucket (1<<SH)
#define NBKT 196                  // ceil(100000/512)
#define BPB 8                     // blocks (and sum replicas) per bucket
#define NB_S 782                  // ceil(E / 4096) hist/scatter blocks

// ---------------- kernel 1: fold W with attn_l/attn_r -> wlr[256][16] ----------------
__global__ void k_wlr(const float* __restrict__ W, const float* __restrict__ al,
                      const float* __restrict__ ar, float* __restrict__ wlr) {
    int t = blockIdx.x * blockDim.x + threadIdx.x;
    if (t >= 256 * 16) return;
    int k = t >> 4, j = t & 15;
    int h = j & 7;
    const float* av = (j < 8) ? al : ar;
    const float* wrow = W + k * 256 + h * 32;
    float s = 0.f;
#pragma unroll
    for (int f = 0; f < 32; ++f) s += wrow[f] * av[h * 32 + f];
    wlr[k * 16 + j] = s;
}

// ---------------- kernel 2: el/er = feat @ wlr (one wave per row, split tables) -------
__global__ void __launch_bounds__(256) k_elr(const float* __restrict__ feat,
                                             const float* __restrict__ wlr,
                                             float* __restrict__ el,
                                             float* __restrict__ er) {
    int lane = threadIdx.x & 63;
    int gwave = (blockIdx.x * blockDim.x + threadIdx.x) >> 6;
    int nwaves = (gridDim.x * blockDim.x) >> 6;

    float w[4][16];
#pragma unroll
    for (int i = 0; i < 4; ++i)
#pragma unroll
        for (int j4 = 0; j4 < 4; ++j4) {
            float4 v = *(const float4*)(wlr + (lane * 4 + i) * 16 + j4 * 4);
            w[i][j4 * 4 + 0] = v.x; w[i][j4 * 4 + 1] = v.y;
            w[i][j4 * 4 + 2] = v.z; w[i][j4 * 4 + 3] = v.w;
        }

    for (int row = gwave; row < N_NODES; row += nwaves) {
        float4 f4 = *(const float4*)(feat + row * 256 + lane * 4);
        float acc[16];
#pragma unroll
        for (int j = 0; j < 16; ++j)
            acc[j] = f4.x * w[0][j] + f4.y * w[1][j] + f4.z * w[2][j] + f4.w * w[3][j];
#pragma unroll
        for (int m = 1; m < 64; m <<= 1)
#pragma unroll
            for (int j = 0; j < 16; ++j)
                acc[j] += __shfl_xor(acc[j], m, 64);
        if (lane == 0) {
            float4* o = (float4*)(el + row * 8);
            o[0] = make_float4(acc[0], acc[1], acc[2], acc[3]);
            o[1] = make_float4(acc[4], acc[5], acc[6], acc[7]);
            float4* p = (float4*)(er + row * 8);
            p[0] = make_float4(acc[8], acc[9], acc[10], acc[11]);
            p[1] = make_float4(acc[12], acc[13], acc[14], acc[15]);
        }
    }
}

// ---------------- bucket histogram (coarse: dst>>SH) ----------------
__global__ void __launch_bounds__(256) k_hist(const int* __restrict__ dst,
                                              int* __restrict__ bktcnt) {
    __shared__ int h[NBKT];
    for (int i = threadIdx.x; i < NBKT; i += 256) h[i] = 0;
    __syncthreads();
    int base = blockIdx.x * 4096;
#pragma unroll
    for (int i = 0; i < 16; ++i) {
        int e = base + i * 256 + threadIdx.x;
        if (e < N_EDGES) atomicAdd(&h[dst[e] >> SH], 1);
    }
    __syncthreads();
    for (int i = threadIdx.x; i < NBKT; i += 256)
        if (h[i]) atomicAdd(&bktcnt[i], h[i]);
}

// ---------------- bucket offsets scan (1 block) ----------------
__global__ void k_bscan(const int* __restrict__ bktcnt, int* __restrict__ bktofs,
                        int* __restrict__ bktcur) {
    __shared__ int s[256];
    int t = threadIdx.x;
    int x = (t < NBKT) ? bktcnt[t] : 0;
    s[t] = x;
    __syncthreads();
    int v = x;
    for (int d = 1; d < 256; d <<= 1) {
        int y = (t >= d) ? s[t - d] : 0;
        __syncthreads();
        v += y;
        s[t] = v;
        __syncthreads();
    }
    if (t < NBKT) { bktofs[t] = v - x; bktcur[t] = v - x; }
    if (t == 0) bktofs[NBKT] = N_EDGES;
}

// ---------------- block-aggregated bucket scatter: packed = (dloc<<17)|src ------------
__global__ void __launch_bounds__(256) k_scat(const int* __restrict__ src,
                                              const int* __restrict__ dst,
                                              int* __restrict__ bktcur,
                                              unsigned* __restrict__ packed) {
    __shared__ int lh[NBKT];
    __shared__ int lbase[NBKT];
    for (int i = threadIdx.x; i < NBKT; i += 256) lh[i] = 0;
    __syncthreads();
    int base = blockIdx.x * 4096;
    int dv[16];
#pragma unroll
    for (int i = 0; i < 16; ++i) {
        int e = base + i * 256 + threadIdx.x;
        dv[i] = (e < N_EDGES) ? dst[e] : -1;
        if (dv[i] >= 0) atomicAdd(&lh[dv[i] >> SH], 1);
    }
    __syncthreads();
    for (int i = threadIdx.x; i < NBKT; i += 256) {
        int c = lh[i];
        lbase[i] = c ? atomicAdd(&bktcur[i], c) : 0;
        lh[i] = 0;
    }
    __syncthreads();
#pragma unroll
    for (int i = 0; i < 16; ++i) {
        int e = base + i * 256 + threadIdx.x;
        if (dv[i] >= 0) {
            int b = dv[i] >> SH;
            int r = atomicAdd(&lh[b], 1);
            unsigned p = ((unsigned)(dv[i] & (RNG - 1)) << 17) | (unsigned)src[e];
            packed[lbase[b] + r] = p;
        }
    }
}

// ---------------- bucketed exp-sum: LDS accumulators, replica flush ----------------
__global__ void __launch_bounds__(256) k_bsum(const unsigned* __restrict__ packed,
                                              const int* __restrict__ bktofs,
                                              const float* __restrict__ el,
                                              const float* __restrict__ er,
                                              float* __restrict__ repl) {
    __shared__ float zss[RNG * 8];          // 16 KB
    int b = blockIdx.x / BPB, q = blockIdx.x % BPB;
    int nbase = b << SH;
    int nlim = min(RNG, N_NODES - nbase);
    for (int i = threadIdx.x; i < RNG * 8; i += 256) zss[i] = 0.f;
    __syncthreads();
    int beg = bktofs[b], end = bktofs[b + 1];
    int len = end - beg;
    int chunk = (len + BPB - 1) / BPB;
    int s0 = beg + q * chunk, s1 = min(s0 + chunk, end);
    int g = threadIdx.x >> 3, h = threadIdx.x & 7;

    for (int i = s0 + g; i < s1; i += 128) {          // 4-way unrolled, 32 groups
        unsigned p[4];
#pragma unroll
        for (int u = 0; u < 4; ++u) {
            int idx = i + u * 32;
            p[u] = (idx < s1) ? packed[idx] : 0xFFFFFFFFu;
        }
        float a[4], bb[4];
#pragma unroll
        for (int u = 0; u < 4; ++u)
            if (p[u] != 0xFFFFFFFFu) {
                a[u]  = el[(p[u] & 0x1FFFF) * 8 + h];             // 3.2MB, L2-resident
                bb[u] = er[(nbase + (p[u] >> 17)) * 8 + h];       // 16KB slice, L1-hot
            }
#pragma unroll
        for (int u = 0; u < 4; ++u)
            if (p[u] != 0xFFFFFFFFu) {
                float v = a[u] + bb[u];
                v = v > 0.f ? v : NEG_SLOPE * v;
                atomicAdd(&zss[(p[u] >> 17) * 8 + h], __expf(v));
            }
    }
    __syncthreads();
    float* r = repl + (size_t)q * (N_NODES * 8) + (size_t)nbase * 8;
    for (int i = threadIdx.x; i < nlim * 8; i += 256) r[i] = zss[i];
}

// ---------------- fold replicas -> dstpack[n][16] = {er[0..7], 1/s[0..7]} -------------
__global__ void k_reduce(const float* __restrict__ repl, const float* __restrict__ er,
                         float* __restrict__ dstpack) {
    int i = blockIdx.x * 256 + threadIdx.x;     // i < N*8 (exact grid)
    float s = 0.f;
#pragma unroll
    for (int q = 0; q < BPB; ++q) s += repl[(size_t)q * (N_NODES * 8) + i];
    int n = i >> 3, h = i & 7;
    dstpack[n * 16 + h] = er[i];
    dstpack[n * 16 + 8 + h] = 1.0f / s;
}

// ---------------- streaming normalize: 1 thread/edge, float4 IO ----------------
__device__ __forceinline__ float gatt(float a, float b, float rs) {
    float v = a + b;
    v = v > 0.f ? v : NEG_SLOPE * v;
    return __expf(v) * rs;
}

__global__ void __launch_bounds__(256) k_norm2(const int* __restrict__ src,
                                               const int* __restrict__ dst,
                                               const float* __restrict__ el,
                                               const float* __restrict__ dstpack,
                                               float* __restrict__ out) {
    int e = blockIdx.x * 256 + threadIdx.x;     // 12500 blocks exact
    int sn = src[e], dn = dst[e];
    const float4* ap = (const float4*)(el + sn * 8);
    float4 a0 = ap[0], a1 = ap[1];
    const float4* dp = (const float4*)(dstpack + (size_t)dn * 16);
    float4 e0 = dp[0], e1 = dp[1], r0 = dp[2], r1 = dp[3];
    float4 o0, o1;
    o0.x = gatt(a0.x, e0.x, r0.x); o0.y = gatt(a0.y, e0.y, r0.y);
    o0.z = gatt(a0.z, e0.z, r0.z); o0.w = gatt(a0.w, e0.w, r0.w);
    o1.x = gatt(a1.x, e1.x, r1.x); o1.y = gatt(a1.y, e1.y, r1.y);
    o1.z = gatt(a1.z, e1.z, r1.z); o1.w = gatt(a1.w, e1.w, r1.w);
    float4* op = (float4*)(out + (size_t)e * 8);
    op[0] = o0; op[1] = o1;
}

extern "C" void kernel_launch(void* const* d_in, const int* in_sizes, int n_in,
                              void* d_out, int out_size, void* d_ws, size_t ws_size,
                              hipStream_t stream) {
    const float* feat = (const float*)d_in[0];
    const float* W    = (const float*)d_in[1];
    const float* al   = (const float*)d_in[2];
    const float* ar   = (const float*)d_in[3];
    const int*   src  = (const int*)d_in[4];
    const int*   dst  = (const int*)d_in[5];
    float* out = (float*)d_out;

    // ws layout (~13 MB)
    char* ws = (char*)d_ws;
    float* wlr     = (float*)ws;                                        // 16 KB
    float* el      = (float*)(ws + 16384);                              // 3.2 MB
    float* er      = (float*)(ws + 16384 + (size_t)N_NODES * 8 * 4);    // 3.2 MB
    float* dstpack = (float*)(ws + 16384 + 2 * (size_t)N_NODES * 8 * 4);// 6.4 MB
    char*  ip      = ws + 16384 + 2 * (size_t)N_NODES * 8 * 4 + (size_t)N_NODES * 16 * 4;
    int* bktcnt = (int*)ip;
    int* bktofs = (int*)(ip + 1024);
    int* bktcur = (int*)(ip + 2048);

    // d_out doubles as scratch before the final full overwrite:
    unsigned* packed = (unsigned*)d_out;                 // [E) u32 (12.8 MB)
    float*    repl   = (float*)d_out + N_EDGES;          // [BPB][N*8] f32 (25.6 MB)

    hipMemsetAsync(bktcnt, 0, NBKT * 4, stream);

    k_wlr<<<16, 256, 0, stream>>>(W, al, ar, wlr);
    k_hist<<<NB_S, 256, 0, stream>>>(dst, bktcnt);
    k_bscan<<<1, 256, 0, stream>>>(bktcnt, bktofs, bktcur);
    k_scat<<<NB_S, 256, 0, stream>>>(src, dst, bktcur, packed);
    k_elr<<<2048, 256, 0, stream>>>(feat, wlr, el, er);
    k_bsum<<<NBKT * BPB, 256, 0, stream>>>(packed, bktofs, el, er, repl);
    k_reduce<<<(N_NODES * 8) / 256, 256, 0, stream>>>(repl, er, dstpack);
    k_norm2<<<N_EDGES / 256, 256, 0, stream>>>(src, dst, el, dstpack, out);
}